// Round 8
// baseline (321.837 us; speedup 1.0000x reference)
//
#include <hip/hip_runtime.h>

#define NN 50000
#define EE 800000
#define NEG 0.2f
#define NBG 391         // gemm grid: 1564 waves x 2 mtiles >= 3125
#define NBT 392         // tail grid: 1568 waves x 2 mtiles >= 3125
#define NBKT 391        // dst buckets of 128 nodes
#define EPB 4096        // edges per binA block
#define NSEG 196        // ceil(EE/EPB)

typedef __attribute__((ext_vector_type(8))) short s8;
typedef __attribute__((ext_vector_type(4))) float f4;

__device__ __forceinline__ float leaky(float x) { return x > 0.f ? x : NEG * x; }
__device__ __forceinline__ unsigned bf16r(float x) {
    unsigned u = __float_as_uint(x);
    return (u + 0x7fffu + ((u >> 16) & 1u)) >> 16;
}
__device__ __forceinline__ float lo16(unsigned p) { return __uint_as_float(p << 16); }
__device__ __forceinline__ float hi16(unsigned p) { return __uint_as_float(p & 0xffff0000u); }

__device__ __forceinline__ s8 a_from_f32(const float* p) {
    float4 u = *reinterpret_cast<const float4*>(p);
    float4 v = *reinterpret_cast<const float4*>(p + 4);
    s8 r;
    r[0] = (short)bf16r(u.x); r[1] = (short)bf16r(u.y);
    r[2] = (short)bf16r(u.z); r[3] = (short)bf16r(u.w);
    r[4] = (short)bf16r(v.x); r[5] = (short)bf16r(v.y);
    r[6] = (short)bf16r(v.z); r[7] = (short)bf16r(v.w);
    return r;
}

// ======= fused: blocks [0,NSEG) = binA counting sort by dst>>7 (latency hidden
//         under projection); blocks [NSEG,..) = projection + GAT-l0 pre =======
__global__ __launch_bounds__(256) void k_binA_pre(
        const int* __restrict__ src, const int* __restrict__ dst,
        int* __restrict__ seg_off, int* __restrict__ seg_cnt,
        unsigned* __restrict__ gseg, int* __restrict__ bucket_tot,
        const float* __restrict__ feat, const int* __restrict__ types,
        const float* __restrict__ Wp, const float* __restrict__ bp,
        const float* __restrict__ Wd, const float* __restrict__ bd,
        const float* __restrict__ gW, const float* __restrict__ al,
        const float* __restrict__ ar,
        float* __restrict__ h0f, unsigned* __restrict__ P,
        float* __restrict__ el, float* __restrict__ er) {
    __shared__ unsigned short WpT[64 * 136];   // 17408 B
    __shared__ unsigned short WdT[64 * 72];    // 9216 B
    __shared__ unsigned short WgT[64 * 72];    // 9216 B
    __shared__ unsigned short y0s[4][16 * 72]; // 9216 B
    if (blockIdx.x < NSEG) {
        // ---- binA: block-local counting sort; LDS aliases weight arrays ----
        unsigned* sbuf = (unsigned*)WpT;   // EPB uns  (16384 <= 17408)
        int* cnt = (int*)WdT;              // NBKT+1 ints (1568 <= 9216)
        int* pre = (int*)WgT;              // 512 ints   (2048 <= 9216)
        int* ssc = (int*)y0s;              // 256 ints   (1024 <= 9216)
        for (int i = threadIdx.x; i < NBKT; i += 256) cnt[i] = 0;
        __syncthreads();
        int e0 = blockIdx.x * EPB;
        int nE = EE - e0; if (nE > EPB) nE = EPB;
        int b[16]; unsigned val[16]; int rk[16];
        #pragma unroll
        for (int i = 0; i < 16; i++) {
            int li = i * 256 + threadIdx.x;
            if (li < nE) {
                int e = e0 + li;
                int d = dst[e], s = src[e];
                b[i] = d >> 7;
                val[i] = ((unsigned)s << 7) | (unsigned)(d & 127);
                rk[i] = atomicAdd(&cnt[b[i]], 1);
            } else b[i] = -1;
        }
        __syncthreads();
        int t = threadIdx.x;
        // pair-scan over 512 (>= NBKT) with 256 threads
        int c0 = (2 * t     < NBKT) ? cnt[2 * t]     : 0;
        int c1 = (2 * t + 1 < NBKT) ? cnt[2 * t + 1] : 0;
        ssc[t] = c0 + c1;
        __syncthreads();
        for (int off = 1; off < 256; off <<= 1) {
            int u = (t >= off) ? ssc[t - off] : 0;
            __syncthreads();
            ssc[t] += u;
            __syncthreads();
        }
        int base = ssc[t] - (c0 + c1);
        pre[2 * t] = base;
        pre[2 * t + 1] = base + c0;
        __syncthreads();
        #pragma unroll
        for (int i = 0; i < 16; i++)
            if (b[i] >= 0) sbuf[pre[b[i]] + rk[i]] = val[i];
        for (int i = t; i < NBKT; i += 256) {
            seg_off[blockIdx.x * NBKT + i] = pre[i];
            seg_cnt[blockIdx.x * NBKT + i] = cnt[i];
            atomicAdd(&bucket_tot[i], cnt[i]);
        }
        __syncthreads();
        for (int i = t; i < nE; i += 256)
            gseg[(size_t)blockIdx.x * EPB + i] = sbuf[i];
        return;
    }
    // ---- projection + GAT-l0 pre (MFMA), 2 mtiles per wave ----
    for (int idx = threadIdx.x; idx < 128 * 64; idx += 256) {
        int k = idx >> 6, n = idx & 63;
        WpT[n * 136 + k] = (unsigned short)bf16r(Wp[idx]);
    }
    for (int idx = threadIdx.x; idx < 64 * 64; idx += 256) {
        int k = idx >> 6, n = idx & 63;
        WdT[n * 72 + k] = (unsigned short)bf16r(Wd[idx]);
        WgT[n * 72 + k] = (unsigned short)bf16r(gW[idx]);
    }
    __syncthreads();
    int wv = threadIdx.x >> 6, lane = threadIdx.x & 63;
    int quad = lane >> 4, l16 = lane & 15;
    int gw2 = (blockIdx.x - NSEG) * 4 + wv;
    int mtEnd = gw2 * 2 + 2; if (mtEnd > 3125) mtEnd = 3125;
    for (int mt = gw2 * 2; mt < mtEnd; mt++) {
        int row0 = mt * 16;
        const float* arow = feat + (size_t)(row0 + l16) * 128;
        f4 accp[4], accd[4];
        #pragma unroll
        for (int t = 0; t < 4; t++) { accp[t] = f4{0.f,0.f,0.f,0.f}; accd[t] = f4{0.f,0.f,0.f,0.f}; }
        #pragma unroll
        for (int ks = 0; ks < 4; ks++) {
            s8 a = a_from_f32(arow + ks * 32 + quad * 8);
            #pragma unroll
            for (int t = 0; t < 4; t++) {
                s8 b = *(const s8*)&WpT[(t * 16 + l16) * 136 + ks * 32 + quad * 8];
                accp[t] = __builtin_amdgcn_mfma_f32_16x16x32_bf16(a, b, accp[t], 0, 0, 0);
                if (ks < 2) {
                    s8 bd_ = *(const s8*)&WdT[(t * 16 + l16) * 72 + ks * 32 + quad * 8];
                    accd[t] = __builtin_amdgcn_mfma_f32_16x16x32_bf16(a, bd_, accd[t], 0, 0, 0);
                }
            }
        }
        int ty[4];
        #pragma unroll
        for (int r = 0; r < 4; r++) ty[r] = types[row0 + quad * 4 + r];
        float vv[4][4];
        #pragma unroll
        for (int t = 0; t < 4; t++) {
            int col = t * 16 + l16;
            float bpv = bp[col], bdv = bd[col];
            #pragma unroll
            for (int r = 0; r < 4; r++) {
                float v = ty[r] ? (accd[t][r] + bdv) : (accp[t][r] + bpv);
                vv[t][r] = v;
                h0f[(size_t)(row0 + quad * 4 + r) * 64 + col] = v;
                y0s[wv][(quad * 4 + r) * 72 + col] = (unsigned short)bf16r(v);
            }
        }
        s8 a0 = *(const s8*)&y0s[wv][l16 * 72 + quad * 8];
        s8 a1 = *(const s8*)&y0s[wv][l16 * 72 + 32 + quad * 8];
        f4 hw[4];
        #pragma unroll
        for (int t = 0; t < 4; t++) {
            hw[t] = f4{0.f,0.f,0.f,0.f};
            s8 b0 = *(const s8*)&WgT[(t * 16 + l16) * 72 + quad * 8];
            hw[t] = __builtin_amdgcn_mfma_f32_16x16x32_bf16(a0, b0, hw[t], 0, 0, 0);
            s8 b1_ = *(const s8*)&WgT[(t * 16 + l16) * 72 + 32 + quad * 8];
            hw[t] = __builtin_amdgcn_mfma_f32_16x16x32_bf16(a1, b1_, hw[t], 0, 0, 0);
        }
        #pragma unroll
        for (int t = 0; t < 4; t++) {
            int col = t * 16 + l16;
            float alv = al[col], arv = ar[col];
            #pragma unroll
            for (int r = 0; r < 4; r++) {
                int row = row0 + quad * 4 + r;
                float h = hw[t][r];
                P[(size_t)row * 64 + col] = bf16r(h) | (bf16r(vv[t][r]) << 16);
                float pl = h * alv, pr = h * arv;
                #pragma unroll
                for (int m = 1; m < 16; m <<= 1) {
                    pl += __shfl_xor(pl, m, 64);
                    pr += __shfl_xor(pr, m, 64);
                }
                if (l16 == 0) {
                    el[(size_t)row * 4 + t] = pl;
                    er[(size_t)row * 4 + t] = pr;
                }
            }
        }
    }
}

// ======= binB: per-bucket CSR fill (local degree hist + scan + gather), standalone ======
__global__ __launch_bounds__(256) void k_binB(
        int* __restrict__ row_start, const int* __restrict__ seg_off,
        const int* __restrict__ seg_cnt, const unsigned* __restrict__ gseg,
        int* __restrict__ csr_src, const int* __restrict__ bucket_tot) {
    __shared__ int spre[256];
    __shared__ int soff[NSEG];
    __shared__ int ss[256];
    __shared__ int kur[128];
    __shared__ int sred[4];
    int b = blockIdx.x;
    int t = threadIdx.x;
    int bt = 0;
    for (int i = t; i < b; i += 256) bt += bucket_tot[i];
    #pragma unroll
    for (int o2 = 1; o2 < 64; o2 <<= 1) bt += __shfl_xor(bt, o2, 64);
    if ((t & 63) == 0) sred[t >> 6] = bt;
    int c0 = (t < NSEG) ? seg_cnt[t * NBKT + b] : 0;
    if (t < NSEG) soff[t] = seg_off[t * NBKT + b];
    ss[t] = c0;
    __syncthreads();
    int bstart = sred[0] + sred[1] + sred[2] + sred[3];
    for (int off = 1; off < 256; off <<= 1) {
        int u = (t >= off) ? ss[t - off] : 0;
        __syncthreads();
        ss[t] += u;
        __syncthreads();
    }
    spre[t] = ss[t] - c0;
    int cntb = ss[255];
    if (t < 128) kur[t] = 0;
    __syncthreads();
    for (int idx = t; idx < cntb; idx += 256) {
        int lo = 0, hi = 255;
        #pragma unroll
        for (int s = 0; s < 8; s++) {
            int mid = (lo + hi + 1) >> 1;
            if (spre[mid] <= idx) lo = mid; else hi = mid - 1;
        }
        unsigned v = gseg[(size_t)lo * EPB + soff[lo] + (idx - spre[lo])];
        atomicAdd(&kur[v & 127], 1);
    }
    __syncthreads();
    int deg = (t < 128) ? kur[t] : 0;
    ss[t] = deg;
    __syncthreads();
    for (int off = 1; off < 256; off <<= 1) {
        int u = (t >= off) ? ss[t - off] : 0;
        __syncthreads();
        ss[t] += u;
        __syncthreads();
    }
    if (t < 128) {
        int cur = bstart + ss[t] - deg;
        kur[t] = cur;
        int d = (b << 7) + t;
        if (d < NN) row_start[d] = cur;
    }
    if (b == 0 && t == 0) row_start[NN] = EE;
    __syncthreads();
    for (int idx = t; idx < cntb; idx += 256) {
        int lo = 0, hi = 255;
        #pragma unroll
        for (int s = 0; s < 8; s++) {
            int mid = (lo + hi + 1) >> 1;
            if (spre[mid] <= idx) lo = mid; else hi = mid - 1;
        }
        unsigned v = gseg[(size_t)lo * EPB + soff[lo] + (idx - spre[lo])];
        int p = atomicAdd(&kur[v & 127], 1);
        csr_src[p] = (int)(v >> 7);
    }
}

// ================= edge walk: 1 node/wave, exp once/edge, packed bf16 gather ======
template <int RELU>
__global__ void k_edges(const int* __restrict__ rows, const int* __restrict__ csr,
                        const unsigned* __restrict__ Pin,
                        const float* __restrict__ el, const float* __restrict__ er,
                        const float* __restrict__ gat_in, const float* __restrict__ gin_in,
                        const float* __restrict__ eps_p,
                        float* __restrict__ vgf, unsigned short* __restrict__ vgb,
                        unsigned short* __restrict__ xb) {
    __shared__ float ews[4][256];
    int wv = threadIdx.x >> 6, lane = threadIdx.x & 63;
    int n = blockIdx.x * 4 + wv;
    int st = rows[n], dg = rows[n + 1] - st;
    int hd = lane >> 4;
    float4 erv = *reinterpret_cast<const float4*>(er + (size_t)n * 4);
    float accg = 0.f, acci = 0.f, ssum = 0.f;
    for (int base = 0; base < dg; base += 64) {
        int rem = dg - base; if (rem > 64) rem = 64;
        int myi = 0;
        if (lane < rem) {
            myi = csr[st + base + lane];
            float4 lv = *reinterpret_cast<const float4*>(el + (size_t)myi * 4);
            float4 ev;
            ev.x = __expf(leaky(lv.x + erv.x));
            ev.y = __expf(leaky(lv.y + erv.y));
            ev.z = __expf(leaky(lv.z + erv.z));
            ev.w = __expf(leaky(lv.w + erv.w));
            *reinterpret_cast<float4*>(&ews[wv][lane * 4]) = ev;
        }
        int j = 0;
        for (; j + 4 <= rem; j += 4) {
            int s0 = __shfl(myi, j, 64),     s1 = __shfl(myi, j + 1, 64);
            int s2 = __shfl(myi, j + 2, 64), s3 = __shfl(myi, j + 3, 64);
            unsigned p0 = Pin[(size_t)s0 * 64 + lane];
            unsigned p1 = Pin[(size_t)s1 * 64 + lane];
            unsigned p2 = Pin[(size_t)s2 * 64 + lane];
            unsigned p3 = Pin[(size_t)s3 * 64 + lane];
            float a0 = ews[wv][(j + 0) * 4 + hd];
            float a1 = ews[wv][(j + 1) * 4 + hd];
            float a2 = ews[wv][(j + 2) * 4 + hd];
            float a3 = ews[wv][(j + 3) * 4 + hd];
            accg += a0 * lo16(p0) + a1 * lo16(p1) + a2 * lo16(p2) + a3 * lo16(p3);
            acci += hi16(p0) + hi16(p1) + hi16(p2) + hi16(p3);
            ssum += a0 + a1 + a2 + a3;
        }
        for (; j < rem; j++) {
            int s0 = __shfl(myi, j, 64);
            unsigned p0 = Pin[(size_t)s0 * 64 + lane];
            float a0 = ews[wv][j * 4 + hd];
            accg += a0 * lo16(p0); acci += hi16(p0); ssum += a0;
        }
    }
    float vg = accg / (ssum + 1e-9f) + gat_in[(size_t)n * 64 + lane];
    if (RELU) vg = fmaxf(vg, 0.f);
    float invd = 1.0f / fmaxf((float)dg, 1.0f);
    float x = (1.0f + eps_p[0]) * gin_in[(size_t)n * 64 + lane] + acci * invd;
    size_t off = (size_t)n * 64 + lane;
    vgf[off] = vg;
    vgb[off] = (unsigned short)bf16r(vg);
    xb[off] = (unsigned short)bf16r(x);
}

// ====== k_mlp0: layer-0 GIN MLP (y1 in LDS) + GAT-l1 pre ======
__global__ __launch_bounds__(256) void k_mlp0(const unsigned short* __restrict__ Gx,
        const unsigned short* __restrict__ Eb,
        const float* __restrict__ W1, const float* __restrict__ b1,
        const float* __restrict__ W2, const float* __restrict__ b2,
        const float* __restrict__ gatW, const float* __restrict__ al,
        const float* __restrict__ ar,
        float* __restrict__ Cf,
        unsigned* __restrict__ P, float* __restrict__ el, float* __restrict__ er) {
    __shared__ unsigned short W1T[64 * 72];
    __shared__ unsigned short W2T[64 * 72];
    __shared__ unsigned short WgT[64 * 72];
    __shared__ unsigned short y1s[4][16 * 72];
    for (int idx = threadIdx.x; idx < 64 * 64; idx += 256) {
        int k = idx >> 6, n = idx & 63;
        W1T[n * 72 + k] = (unsigned short)bf16r(W1[idx]);
        W2T[n * 72 + k] = (unsigned short)bf16r(W2[idx]);
        WgT[n * 72 + k] = (unsigned short)bf16r(gatW[idx]);
    }
    __syncthreads();
    int wv = threadIdx.x >> 6, lane = threadIdx.x & 63;
    int quad = lane >> 4, l16 = lane & 15;
    int gw = blockIdx.x * 4 + wv;
    int mtEnd = gw * 2 + 2; if (mtEnd > 3125) mtEnd = 3125;
    for (int mt = gw * 2; mt < mtEnd; mt++) {
        int row0 = mt * 16;
        const unsigned short* arow = Gx + (size_t)(row0 + l16) * 64;
        s8 a0 = *(const s8*)(arow + quad * 8);
        s8 a1 = *(const s8*)(arow + 32 + quad * 8);
        f4 acc1[4];
        #pragma unroll
        for (int t = 0; t < 4; t++) {
            acc1[t] = f4{0.f,0.f,0.f,0.f};
            s8 b0 = *(const s8*)&W1T[(t * 16 + l16) * 72 + quad * 8];
            acc1[t] = __builtin_amdgcn_mfma_f32_16x16x32_bf16(a0, b0, acc1[t], 0, 0, 0);
            s8 b1_ = *(const s8*)&W1T[(t * 16 + l16) * 72 + 32 + quad * 8];
            acc1[t] = __builtin_amdgcn_mfma_f32_16x16x32_bf16(a1, b1_, acc1[t], 0, 0, 0);
        }
        #pragma unroll
        for (int t = 0; t < 4; t++) {
            float b1v = b1[t * 16 + l16];
            #pragma unroll
            for (int r = 0; r < 4; r++) {
                float v = fmaxf(acc1[t][r] + b1v, 0.f);
                y1s[wv][(quad * 4 + r) * 72 + t * 16 + l16] = (unsigned short)bf16r(v);
            }
        }
        s8 c0 = *(const s8*)&y1s[wv][l16 * 72 + quad * 8];
        s8 c1 = *(const s8*)&y1s[wv][l16 * 72 + 32 + quad * 8];
        f4 acc2[4];
        #pragma unroll
        for (int t = 0; t < 4; t++) {
            acc2[t] = f4{0.f,0.f,0.f,0.f};
            s8 b0 = *(const s8*)&W2T[(t * 16 + l16) * 72 + quad * 8];
            acc2[t] = __builtin_amdgcn_mfma_f32_16x16x32_bf16(c0, b0, acc2[t], 0, 0, 0);
            s8 b1_ = *(const s8*)&W2T[(t * 16 + l16) * 72 + 32 + quad * 8];
            acc2[t] = __builtin_amdgcn_mfma_f32_16x16x32_bf16(c1, b1_, acc2[t], 0, 0, 0);
        }
        unsigned short vb[4][4];
        #pragma unroll
        for (int t = 0; t < 4; t++) {
            int col = t * 16 + l16;
            float b2v = b2[col];
            #pragma unroll
            for (int r = 0; r < 4; r++) {
                float v = fmaxf(acc2[t][r] + b2v, 0.f);   // relu (layer 0)
                size_t off = (size_t)(row0 + quad * 4 + r) * 64 + col;
                vb[t][r] = (unsigned short)bf16r(v);
                Cf[off] = v;
            }
        }
        const unsigned short* erow = Eb + (size_t)(row0 + l16) * 64;
        s8 e0 = *(const s8*)(erow + quad * 8);
        s8 e1 = *(const s8*)(erow + 32 + quad * 8);
        f4 hw[4];
        #pragma unroll
        for (int t = 0; t < 4; t++) {
            hw[t] = f4{0.f,0.f,0.f,0.f};
            s8 b0 = *(const s8*)&WgT[(t * 16 + l16) * 72 + quad * 8];
            hw[t] = __builtin_amdgcn_mfma_f32_16x16x32_bf16(e0, b0, hw[t], 0, 0, 0);
            s8 b1_ = *(const s8*)&WgT[(t * 16 + l16) * 72 + 32 + quad * 8];
            hw[t] = __builtin_amdgcn_mfma_f32_16x16x32_bf16(e1, b1_, hw[t], 0, 0, 0);
        }
        #pragma unroll
        for (int t = 0; t < 4; t++) {
            int col = t * 16 + l16;
            float alv = al[col], arv = ar[col];
            #pragma unroll
            for (int r = 0; r < 4; r++) {
                int row = row0 + quad * 4 + r;
                float h = hw[t][r];
                P[(size_t)row * 64 + col] = bf16r(h) | ((unsigned)vb[t][r] << 16);
                float pl = h * alv, pr = h * arv;
                #pragma unroll
                for (int m = 1; m < 16; m <<= 1) {
                    pl += __shfl_xor(pl, m, 64);
                    pr += __shfl_xor(pr, m, 64);
                }
                if (l16 == 0) {
                    el[(size_t)row * 4 + t] = pl;
                    er[(size_t)row * 4 + t] = pr;
                }
            }
        }
    }
}

// ======= k_tail: gin-l1 MLP + MoE routing + dense experts (both) + fusion + aux =======
__global__ __launch_bounds__(256) void k_tail(
        const unsigned short* __restrict__ Gx,   // xb (gin l1 MLP input)
        const unsigned short* __restrict__ Eb,   // vg l1 bf16 (gat expert input)
        const float* __restrict__ Zg,            // vg l1 f32 (gat routing input)
        const float* __restrict__ mW1, const float* __restrict__ mb1,
        const float* __restrict__ mW2, const float* __restrict__ mb2,
        const float* __restrict__ ggW, const float* __restrict__ ggb,
        const float* __restrict__ igW, const float* __restrict__ igb,
        const float* __restrict__ g_eW1, const float* __restrict__ g_eb1,
        const float* __restrict__ g_eW2, const float* __restrict__ g_eb2,
        const float* __restrict__ i_eW1, const float* __restrict__ i_eb1,
        const float* __restrict__ i_eW2, const float* __restrict__ i_eb2,
        const float* __restrict__ W1, const float* __restrict__ b1,
        const float* __restrict__ W2, const float* __restrict__ b2,
        unsigned short* __restrict__ ub, float* __restrict__ out,
        float* __restrict__ stats, unsigned* __restrict__ done) {
    __shared__ unsigned short wbuf[4 * 32 * 72 + 4 * 64 * 40];  // 38912 B, multi-phase alias
    __shared__ unsigned short y1s[4][16 * 72];                  // 9216 B
    __shared__ float wqs[4][2][32][4];                          // 4096 B routing weights
    __shared__ float sstat[16];
    if (threadIdx.x < 16) sstat[threadIdx.x] = 0.f;
    // ---- phase 1: stage gin-l1 MLP weights (aliases expert region) ----
    for (int idx = threadIdx.x; idx < 64 * 64; idx += 256) {
        int k = idx >> 6, n = idx & 63;
        wbuf[n * 72 + k] = (unsigned short)bf16r(mW1[idx]);         // W1T [0,4608)
        wbuf[4608 + n * 72 + k] = (unsigned short)bf16r(mW2[idx]);  // W2T [4608,9216)
    }
    __syncthreads();
    int wv = threadIdx.x >> 6, lane = threadIdx.x & 63;
    int quad = lane >> 4, l16 = lane & 15;
    int gw = blockIdx.x * 4 + wv;
    int mt0 = gw * 2;
    float sp[2][4] = {{0,0,0,0},{0,0,0,0}};
    float sh[2][4] = {{0,0,0,0},{0,0,0,0}};
    s8 ai0_0{}, ai1_0{}, ai0_1{}, ai1_1{};   // gin A-frags per mtile (static names, rule #20)
    // ---- phase 2: gin-l1 MLP + routing, per mtile ----
    #pragma unroll
    for (int m = 0; m < 2; m++) {
        int mt = mt0 + m;
        if (mt < 3125) {
            int row0 = mt * 16;
            const unsigned short* arow = Gx + (size_t)(row0 + l16) * 64;
            s8 a0 = *(const s8*)(arow + quad * 8);
            s8 a1 = *(const s8*)(arow + 32 + quad * 8);
            f4 acc1[4];
            #pragma unroll
            for (int t = 0; t < 4; t++) {
                acc1[t] = f4{0.f,0.f,0.f,0.f};
                s8 b0 = *(const s8*)&wbuf[(t * 16 + l16) * 72 + quad * 8];
                acc1[t] = __builtin_amdgcn_mfma_f32_16x16x32_bf16(a0, b0, acc1[t], 0, 0, 0);
                s8 b1_ = *(const s8*)&wbuf[(t * 16 + l16) * 72 + 32 + quad * 8];
                acc1[t] = __builtin_amdgcn_mfma_f32_16x16x32_bf16(a1, b1_, acc1[t], 0, 0, 0);
            }
            #pragma unroll
            for (int t = 0; t < 4; t++) {
                float b1v = mb1[t * 16 + l16];
                #pragma unroll
                for (int r = 0; r < 4; r++) {
                    float v = fmaxf(acc1[t][r] + b1v, 0.f);
                    y1s[wv][(quad * 4 + r) * 72 + t * 16 + l16] = (unsigned short)bf16r(v);
                }
            }
            s8 c0 = *(const s8*)&y1s[wv][l16 * 72 + quad * 8];
            s8 c1 = *(const s8*)&y1s[wv][l16 * 72 + 32 + quad * 8];
            f4 acc2[4];
            #pragma unroll
            for (int t = 0; t < 4; t++) {
                acc2[t] = f4{0.f,0.f,0.f,0.f};
                s8 b0 = *(const s8*)&wbuf[4608 + (t * 16 + l16) * 72 + quad * 8];
                acc2[t] = __builtin_amdgcn_mfma_f32_16x16x32_bf16(c0, b0, acc2[t], 0, 0, 0);
                s8 b1_ = *(const s8*)&wbuf[4608 + (t * 16 + l16) * 72 + 32 + quad * 8];
                acc2[t] = __builtin_amdgcn_mfma_f32_16x16x32_bf16(c1, b1_, acc2[t], 0, 0, 0);
            }
            float vout[4][4];
            #pragma unroll
            for (int t = 0; t < 4; t++) {
                float b2v = mb2[t * 16 + l16];
                #pragma unroll
                for (int r = 0; r < 4; r++) vout[t][r] = acc2[t][r] + b2v;  // no relu (last layer)
            }
            // transpose vout -> LDS -> gin A-frags for expert phase (bit-identical bf16)
            #pragma unroll
            for (int t = 0; t < 4; t++)
                #pragma unroll
                for (int r = 0; r < 4; r++)
                    y1s[wv][(quad * 4 + r) * 72 + t * 16 + l16] = (unsigned short)bf16r(vout[t][r]);
            if (m == 0) {
                ai0_0 = *(const s8*)&y1s[wv][l16 * 72 + quad * 8];
                ai1_0 = *(const s8*)&y1s[wv][l16 * 72 + 32 + quad * 8];
            } else {
                ai0_1 = *(const s8*)&y1s[wv][l16 * 72 + quad * 8];
                ai1_1 = *(const s8*)&y1s[wv][l16 * 72 + 32 + quad * 8];
            }
            // MoE routing: zg from global (f32), zi from registers
            #pragma unroll
            for (int r = 0; r < 4; r++) {
                int row = row0 + quad * 4 + r;
                float pg[4] = {0,0,0,0}, pi[4] = {0,0,0,0};
                #pragma unroll
                for (int t = 0; t < 4; t++) {
                    int col = t * 16 + l16;
                    float zgv = Zg[(size_t)row * 64 + col];
                    float ziv = vout[t][r];
                    #pragma unroll
                    for (int e = 0; e < 4; e++) {
                        pg[e] += zgv * ggW[col * 4 + e];
                        pi[e] += ziv * igW[col * 4 + e];
                    }
                }
                #pragma unroll
                for (int mm = 1; mm < 16; mm <<= 1) {
                    #pragma unroll
                    for (int e = 0; e < 4; e++) {
                        pg[e] += __shfl_xor(pg[e], mm, 64);
                        pi[e] += __shfl_xor(pi[e], mm, 64);
                    }
                }
                if (l16 == 0) {
                    #pragma unroll
                    for (int q = 0; q < 2; q++) {
                        float lg0 = (q ? pi[0] + igb[0] : pg[0] + ggb[0]);
                        float lg1 = (q ? pi[1] + igb[1] : pg[1] + ggb[1]);
                        float lg2 = (q ? pi[2] + igb[2] : pg[2] + ggb[2]);
                        float lg3 = (q ? pi[3] + igb[3] : pg[3] + ggb[3]);
                        float mx = fmaxf(fmaxf(lg0, lg1), fmaxf(lg2, lg3));
                        float ex0 = __expf(lg0 - mx), ex1 = __expf(lg1 - mx);
                        float ex2 = __expf(lg2 - mx), ex3 = __expf(lg3 - mx);
                        float inv = 1.0f / (ex0 + ex1 + ex2 + ex3);
                        float pr4[4] = {ex0 * inv, ex1 * inv, ex2 * inv, ex3 * inv};
                        int i1 = 0; float v1 = pr4[0];
                        #pragma unroll
                        for (int t = 1; t < 4; t++) if (pr4[t] > v1) { v1 = pr4[t]; i1 = t; }
                        int i2 = -1; float v2 = -1.f;
                        #pragma unroll
                        for (int t = 0; t < 4; t++) if (t != i1 && pr4[t] > v2) { v2 = pr4[t]; i2 = t; }
                        float wsum = v1 + v2;
                        float wq[4] = {0.f, 0.f, 0.f, 0.f};
                        wq[i1] = v1 / wsum; wq[i2] = v2 / wsum;
                        #pragma unroll
                        for (int e = 0; e < 4; e++) wqs[wv][q][m * 16 + quad * 4 + r][e] = wq[e];
                        #pragma unroll
                        for (int t = 0; t < 4; t++) sp[q][t] += pr4[t];
                        sh[q][i1] += 1.f; sh[q][i2] += 1.f;
                    }
                }
            }
        }
    }
    // ---- phase 3: stats + last-block aux finalize ----
    __syncthreads();
    if (l16 == 0) {
        #pragma unroll
        for (int q = 0; q < 2; q++)
            #pragma unroll
            for (int e = 0; e < 4; e++) {
                atomicAdd(&sstat[q * 8 + e], sp[q][e]);
                atomicAdd(&sstat[q * 8 + 4 + e], sh[q][e]);
            }
    }
    __syncthreads();
    if (threadIdx.x < 16) atomicAdd(&stats[threadIdx.x], sstat[threadIdx.x]);
    __syncthreads();   // drains this block's global atomics (s_waitcnt before barrier)
    if (threadIdx.x == 0) {
        unsigned rr = atomicAdd(done, 1u);
        if (rr == (unsigned)(gridDim.x - 1)) {
            float s[16];
            #pragma unroll
            for (int i = 0; i < 16; i++) s[i] = atomicAdd(&stats[i], 0.f);  // coherent read
            float aux = 0.f;
            for (int q = 0; q < 2; q++) {
                float a = 0.f;
                for (int e = 0; e < 4; e++)
                    a += (s[q * 8 + 4 + e] / (float)NN) * (s[q * 8 + e] / (float)NN);
                aux += 4.0f * a;
            }
            out[(size_t)NN * 64] = aux;
        }
    }
    // ---- phase 4: dense experts (both problems) ----
    f4 moe[2][2][4];
    #pragma unroll
    for (int p = 0; p < 2; p++)
        #pragma unroll
        for (int m = 0; m < 2; m++)
            #pragma unroll
            for (int t = 0; t < 4; t++) moe[p][m][t] = f4{0.f,0.f,0.f,0.f};
    #pragma unroll
    for (int p = 0; p < 2; p++) {
        const float* eW1 = p ? i_eW1 : g_eW1;
        const float* eb1 = p ? i_eb1 : g_eb1;
        const float* eW2 = p ? i_eW2 : g_eW2;
        const float* eb2 = p ? i_eb2 : g_eb2;
        int qoff = p ? 64 : 0;
        if (p) __syncthreads();     // drain previous problem's wbuf reads
        for (int g = threadIdx.x; g < 8192; g += 256) {
            int e = g >> 11, rem = g & 2047;
            int k = rem >> 5, n = rem & 31;
            wbuf[e * 2304 + n * 72 + k] = (unsigned short)bf16r(eW1[g]);
        }
        for (int g = threadIdx.x; g < 8192; g += 256) {
            int e = g >> 11, rem = g & 2047;
            int k = rem >> 6, n = rem & 63;
            wbuf[9216 + e * 2560 + n * 40 + k] = (unsigned short)bf16r(eW2[g]);
        }
        __syncthreads();
        #pragma unroll
        for (int m = 0; m < 2; m++) {
            int mt = mt0 + m;
            if (mt < 3125) {
                int row0 = mt * 16;
                s8 a0, a1;
                if (p == 0) {
                    const unsigned short* arow = Eb + (size_t)(row0 + l16) * 64;
                    a0 = *(const s8*)(arow + quad * 8);
                    a1 = *(const s8*)(arow + 32 + quad * 8);
                } else {
                    a0 = (m == 0) ? ai0_0 : ai0_1;
                    a1 = (m == 0) ? ai1_0 : ai1_1;
                }
                for (int e = 0; e < 4; e++) {
                    f4 acc1[2];
                    #pragma unroll
                    for (int t = 0; t < 2; t++) {
                        acc1[t] = f4{0.f,0.f,0.f,0.f};
                        s8 b0 = *(const s8*)&wbuf[e * 2304 + (t * 16 + l16) * 72 + quad * 8];
                        acc1[t] = __builtin_amdgcn_mfma_f32_16x16x32_bf16(a0, b0, acc1[t], 0, 0, 0);
                        s8 b1_ = *(const s8*)&wbuf[e * 2304 + (t * 16 + l16) * 72 + 32 + quad * 8];
                        acc1[t] = __builtin_amdgcn_mfma_f32_16x16x32_bf16(a1, b1_, acc1[t], 0, 0, 0);
                    }
                    #pragma unroll
                    for (int t = 0; t < 2; t++) {
                        float b1v = eb1[e * 32 + t * 16 + l16];
                        #pragma unroll
                        for (int r = 0; r < 4; r++) {
                            float v = fmaxf(acc1[t][r] + b1v, 0.f);
                            y1s[wv][(quad * 4 + r) * 40 + t * 16 + l16] = (unsigned short)bf16r(v);
                        }
                    }
                    s8 a2 = *(const s8*)&y1s[wv][l16 * 40 + quad * 8];
                    f4 acc2[4];
                    #pragma unroll
                    for (int t = 0; t < 4; t++) {
                        acc2[t] = f4{0.f,0.f,0.f,0.f};
                        s8 b2_ = *(const s8*)&wbuf[9216 + e * 2560 + (t * 16 + l16) * 40 + quad * 8];
                        acc2[t] = __builtin_amdgcn_mfma_f32_16x16x32_bf16(a2, b2_, acc2[t], 0, 0, 0);
                    }
                    #pragma unroll
                    for (int t = 0; t < 4; t++) {
                        float b2v = eb2[e * 64 + t * 16 + l16];
                        #pragma unroll
                        for (int r = 0; r < 4; r++) {
                            float we = wqs[wv][p][m * 16 + quad * 4 + r][e];
                            moe[p][m][t][r] += we * (acc2[t][r] + b2v);
                        }
                    }
                }
                #pragma unroll
                for (int t = 0; t < 4; t++) {
                    int col = t * 16 + l16;
                    #pragma unroll
                    for (int r = 0; r < 4; r++) {
                        int row = row0 + quad * 4 + r;
                        ub[(size_t)row * 128 + qoff + col] = (unsigned short)bf16r(moe[p][m][t][r]);
                    }
                }
            }
        }
    }
    __syncthreads();
    // ---- phase 5: fusion gate (weights alias wbuf) ----
    for (int idx = threadIdx.x; idx < 128 * 64; idx += 256) {
        int k = idx >> 6, n = idx & 63;
        wbuf[n * 136 + k] = (unsigned short)bf16r(W1[idx]);
    }
    for (int idx = threadIdx.x; idx < 64 * 64; idx += 256) {
        int k = idx >> 6, n = idx & 63;
        wbuf[8704 + n * 72 + k] = (unsigned short)bf16r(W2[idx]);
    }
    __syncthreads();
    #pragma unroll
    for (int m = 0; m < 2; m++) {
        int mt = mt0 + m;
        if (mt < 3125) {
            int row0 = mt * 16;
            const unsigned short* arow = ub + (size_t)(row0 + l16) * 128;
            f4 acc1[4];
            #pragma unroll
            for (int t = 0; t < 4; t++) acc1[t] = f4{0.f,0.f,0.f,0.f};
            #pragma unroll
            for (int ks = 0; ks < 4; ks++) {
                s8 a = *(const s8*)(arow + ks * 32 + quad * 8);
                #pragma unroll
                for (int t = 0; t < 4; t++) {
                    s8 b = *(const s8*)&wbuf[(t * 16 + l16) * 136 + ks * 32 + quad * 8];
                    acc1[t] = __builtin_amdgcn_mfma_f32_16x16x32_bf16(a, b, acc1[t], 0, 0, 0);
                }
            }
            #pragma unroll
            for (int t = 0; t < 4; t++) {
                float b1v = b1[t * 16 + l16];
                #pragma unroll
                for (int r = 0; r < 4; r++) {
                    float v = fmaxf(acc1[t][r] + b1v, 0.f);
                    y1s[wv][(quad * 4 + r) * 72 + t * 16 + l16] = (unsigned short)bf16r(v);
                }
            }
            f4 acc2[4];
            #pragma unroll
            for (int t = 0; t < 4; t++) acc2[t] = f4{0.f,0.f,0.f,0.f};
            #pragma unroll
            for (int ks = 0; ks < 2; ks++) {
                s8 a = *(const s8*)&y1s[wv][l16 * 72 + ks * 32 + quad * 8];
                #pragma unroll
                for (int t = 0; t < 4; t++) {
                    s8 b = *(const s8*)&wbuf[8704 + (t * 16 + l16) * 72 + ks * 32 + quad * 8];
                    acc2[t] = __builtin_amdgcn_mfma_f32_16x16x32_bf16(a, b, acc2[t], 0, 0, 0);
                }
            }
            #pragma unroll
            for (int t = 0; t < 4; t++) {
                int col = t * 16 + l16;
                float b2v = b2[col];
                #pragma unroll
                for (int r = 0; r < 4; r++) {
                    int row = row0 + quad * 4 + r;
                    float g = 1.0f / (1.0f + __expf(-(acc2[t][r] + b2v)));
                    float zgv = moe[0][m][t][r];
                    float ziv = moe[1][m][t][r];
                    out[(size_t)row * 64 + col] = g * zgv * ziv + (1.0f - g) * g;
                }
            }
        }
    }
}

extern "C" void kernel_launch(void* const* d_in, const int* in_sizes, int n_in,
                              void* d_out, int out_size, void* d_ws, size_t ws_size,
                              hipStream_t stream) {
    (void)in_sizes; (void)n_in; (void)out_size; (void)ws_size;
    const float* features  = (const float*)d_in[0];
    const int*   node_types= (const int*)d_in[1];
    const int*   src       = (const int*)d_in[2];
    const int*   dst       = (const int*)d_in[3];
    const float* W_person  = (const float*)d_in[4];
    const float* b_person  = (const float*)d_in[5];
    const float* W_disease = (const float*)d_in[6];
    const float* b_disease = (const float*)d_in[7];
    const float* gat_W     = (const float*)d_in[8];
    const float* gat_al    = (const float*)d_in[9];
    const float* gat_ar    = (const float*)d_in[10];
    const float* gin_eps   = (const float*)d_in[11];
    const float* gin_W1    = (const float*)d_in[12];
    const float* gin_b1    = (const float*)d_in[13];
    const float* gin_W2    = (const float*)d_in[14];
    const float* gin_b2    = (const float*)d_in[15];
    const float* gat_gW    = (const float*)d_in[16];
    const float* gat_gb    = (const float*)d_in[17];
    const float* gat_eW1   = (const float*)d_in[18];
    const float* gat_eb1   = (const float*)d_in[19];
    const float* gat_eW2   = (const float*)d_in[20];
    const float* gat_eb2   = (const float*)d_in[21];
    const float* gin_gW    = (const float*)d_in[22];
    const float* gin_gb    = (const float*)d_in[23];
    const float* gin_eW1   = (const float*)d_in[24];
    const float* gin_eb1   = (const float*)d_in[25];
    const float* gin_eW2   = (const float*)d_in[26];
    const float* gin_eb2   = (const float*)d_in[27];
    const float* fg_W1     = (const float*)d_in[28];
    const float* fg_b1     = (const float*)d_in[29];
    const float* fg_W2     = (const float*)d_in[30];
    const float* fg_b2     = (const float*)d_in[31];
    float* out = (float*)d_out;

    float* ws = (float*)d_ws;
    size_t o = 0;
    float* A = ws + o; o += (size_t)NN * 64;        // h0f; later ub (bf16 NN x 128)
    float* B = ws + o; o += (size_t)NN * 64;        // vg f32 chain (zg for routing)
    float* C = ws + o; o += (size_t)NN * 64;        // gin l0 f32
    unsigned short* E  = (unsigned short*)(ws + o); o += (size_t)NN * 32;  // vgb
    unsigned short* G  = (unsigned short*)(ws + o); o += (size_t)NN * 32;  // xb
    unsigned* P = (unsigned*)(ws + o); o += (size_t)NN * 64;  // packed hW|gin
    float* el = ws + o; o += (size_t)NN * 4;
    float* er = ws + o; o += (size_t)NN * 4;
    // zeroed region: bucket_tot | stats | done (single tiny memset)
    int* bucket_tot = (int*)(ws + o); o += 392;
    float* stats    = ws + o; o += 16;
    unsigned* done  = (unsigned*)(ws + o); o += 4;
    int* row_start = (int*)(ws + o); o += NN + 4;
    int* csr_src   = (int*)(ws + o); o += EE;
    int* seg_off   = (int*)(ws + o); o += NSEG * NBKT + 64;
    int* seg_cnt   = (int*)(ws + o); o += NSEG * NBKT + 64;
    unsigned* gseg = (unsigned*)(ws + o); o += (size_t)NSEG * EPB;

    unsigned short* ub = (unsigned short*)A;  // reuse after edges(l0)

    const int NB_node = NN / 4;     // 12500

    hipMemsetAsync(bucket_tot, 0, sizeof(int) * 392 + sizeof(float) * 16 + 16, stream);

    // fused: binA counting sort (blocks 0..195) || projection/GAT-l0 pre (blocks 196..586)
    k_binA_pre<<<NSEG + NBG, 256, 0, stream>>>(src, dst, seg_off, seg_cnt, gseg, bucket_tot,
                                               features, node_types, W_person, b_person,
                                               W_disease, b_disease, gat_W, gat_al, gat_ar,
                                               A, P, el, er);

    // binB: per-bucket CSR fill (391 blocks, small LDS)
    k_binB<<<NBKT, 256, 0, stream>>>(row_start, seg_off, seg_cnt, gseg, csr_src, bucket_tot);

    // ---- layer 0 ----
    k_edges<1><<<NB_node, 256, 0, stream>>>(row_start, csr_src, P, el, er, A, A,
                                            gin_eps, B, E, G);
    k_mlp0<<<NBG, 256, 0, stream>>>(G, E, gin_W1, gin_b1, gin_W2, gin_b2,
                                    gat_W + 4096, gat_al + 64, gat_ar + 64,
                                    C, P, el, er);

    // ---- layer 1 edges ----
    k_edges<0><<<NB_node, 256, 0, stream>>>(row_start, csr_src, P, el, er, B, C,
                                            gin_eps + 1, B, E, G);

    // ---- tail: gin-l1 MLP + routing + experts (both) + fusion + aux, one kernel ----
    k_tail<<<NBT, 256, 0, stream>>>(G, E, B,
                                    gin_W1 + 4096, gin_b1 + 64, gin_W2 + 4096, gin_b2 + 64,
                                    gat_gW, gat_gb, gin_gW, gin_gb,
                                    gat_eW1, gat_eb1, gat_eW2, gat_eb2,
                                    gin_eW1, gin_eb1, gin_eW2, gin_eb2,
                                    fg_W1, fg_b1, fg_W2, fg_b2,
                                    ub, out, stats, done);
}

// Round 9
// 312.940 us; speedup vs baseline: 1.0284x; 1.0284x over previous
//
#include <hip/hip_runtime.h>

#define NN 50000
#define EE 800000
#define NEG 0.2f
#define NBG 391         // gemm grid: 1564 waves x 2 mtiles >= 3125
#define NBT 392         // tail grid: 1568 waves x 2 mtiles >= 3125
#define NBKT 391        // dst buckets of 128 nodes
#define EPB 4096        // edges per binA block
#define NSEG 196        // ceil(EE/EPB)

typedef __attribute__((ext_vector_type(8))) short s8;
typedef __attribute__((ext_vector_type(4))) float f4;

__device__ __forceinline__ float leaky(float x) { return x > 0.f ? x : NEG * x; }
__device__ __forceinline__ unsigned bf16r(float x) {
    unsigned u = __float_as_uint(x);
    return (u + 0x7fffu + ((u >> 16) & 1u)) >> 16;
}
__device__ __forceinline__ float lo16(unsigned p) { return __uint_as_float(p << 16); }
__device__ __forceinline__ float hi16(unsigned p) { return __uint_as_float(p & 0xffff0000u); }

__device__ __forceinline__ s8 a_from_f32(const float* p) {
    float4 u = *reinterpret_cast<const float4*>(p);
    float4 v = *reinterpret_cast<const float4*>(p + 4);
    s8 r;
    r[0] = (short)bf16r(u.x); r[1] = (short)bf16r(u.y);
    r[2] = (short)bf16r(u.z); r[3] = (short)bf16r(u.w);
    r[4] = (short)bf16r(v.x); r[5] = (short)bf16r(v.y);
    r[6] = (short)bf16r(v.z); r[7] = (short)bf16r(v.w);
    return r;
}

// ======= fused: blocks [0,NSEG) = binA counting sort by dst>>7 (latency hidden
//         under projection); blocks [NSEG,..) = projection + GAT-l0 pre =======
__global__ __launch_bounds__(256) void k_binA_pre(
        const int* __restrict__ src, const int* __restrict__ dst,
        int* __restrict__ seg_off, int* __restrict__ seg_cnt,
        unsigned* __restrict__ gseg, int* __restrict__ bucket_tot,
        const float* __restrict__ feat, const int* __restrict__ types,
        const float* __restrict__ Wp, const float* __restrict__ bp,
        const float* __restrict__ Wd, const float* __restrict__ bd,
        const float* __restrict__ gW, const float* __restrict__ al,
        const float* __restrict__ ar,
        float* __restrict__ h0f, unsigned* __restrict__ P,
        float* __restrict__ el, float* __restrict__ er) {
    __shared__ unsigned short WpT[64 * 136];   // 17408 B
    __shared__ unsigned short WdT[64 * 72];    // 9216 B
    __shared__ unsigned short WgT[64 * 72];    // 9216 B
    __shared__ unsigned short y0s[4][16 * 72]; // 9216 B
    if (blockIdx.x < NSEG) {
        // ---- binA: block-local counting sort; LDS aliases weight arrays ----
        unsigned* sbuf = (unsigned*)WpT;   // EPB uns  (16384 <= 17408)
        int* cnt = (int*)WdT;              // NBKT+1 ints (1568 <= 9216)
        int* pre = (int*)WgT;              // 512 ints   (2048 <= 9216)
        int* ssc = (int*)y0s;              // 256 ints   (1024 <= 9216)
        for (int i = threadIdx.x; i < NBKT; i += 256) cnt[i] = 0;
        __syncthreads();
        int e0 = blockIdx.x * EPB;
        int nE = EE - e0; if (nE > EPB) nE = EPB;
        int b[16]; unsigned val[16]; int rk[16];
        #pragma unroll
        for (int i = 0; i < 16; i++) {
            int li = i * 256 + threadIdx.x;
            if (li < nE) {
                int e = e0 + li;
                int d = dst[e], s = src[e];
                b[i] = d >> 7;
                val[i] = ((unsigned)s << 7) | (unsigned)(d & 127);
                rk[i] = atomicAdd(&cnt[b[i]], 1);
            } else b[i] = -1;
        }
        __syncthreads();
        int t = threadIdx.x;
        // pair-scan over 512 (>= NBKT) with 256 threads
        int c0 = (2 * t     < NBKT) ? cnt[2 * t]     : 0;
        int c1 = (2 * t + 1 < NBKT) ? cnt[2 * t + 1] : 0;
        ssc[t] = c0 + c1;
        __syncthreads();
        for (int off = 1; off < 256; off <<= 1) {
            int u = (t >= off) ? ssc[t - off] : 0;
            __syncthreads();
            ssc[t] += u;
            __syncthreads();
        }
        int base = ssc[t] - (c0 + c1);
        pre[2 * t] = base;
        pre[2 * t + 1] = base + c0;
        __syncthreads();
        #pragma unroll
        for (int i = 0; i < 16; i++)
            if (b[i] >= 0) sbuf[pre[b[i]] + rk[i]] = val[i];
        for (int i = t; i < NBKT; i += 256) {
            seg_off[blockIdx.x * NBKT + i] = pre[i];
            seg_cnt[blockIdx.x * NBKT + i] = cnt[i];
            atomicAdd(&bucket_tot[i], cnt[i]);
        }
        __syncthreads();
        for (int i = t; i < nE; i += 256)
            gseg[(size_t)blockIdx.x * EPB + i] = sbuf[i];
        return;
    }
    // ---- projection + GAT-l0 pre (MFMA), 2 mtiles per wave ----
    for (int idx = threadIdx.x; idx < 128 * 64; idx += 256) {
        int k = idx >> 6, n = idx & 63;
        WpT[n * 136 + k] = (unsigned short)bf16r(Wp[idx]);
    }
    for (int idx = threadIdx.x; idx < 64 * 64; idx += 256) {
        int k = idx >> 6, n = idx & 63;
        WdT[n * 72 + k] = (unsigned short)bf16r(Wd[idx]);
        WgT[n * 72 + k] = (unsigned short)bf16r(gW[idx]);
    }
    __syncthreads();
    int wv = threadIdx.x >> 6, lane = threadIdx.x & 63;
    int quad = lane >> 4, l16 = lane & 15;
    int gw2 = (blockIdx.x - NSEG) * 4 + wv;
    int mtEnd = gw2 * 2 + 2; if (mtEnd > 3125) mtEnd = 3125;
    for (int mt = gw2 * 2; mt < mtEnd; mt++) {
        int row0 = mt * 16;
        const float* arow = feat + (size_t)(row0 + l16) * 128;
        f4 accp[4], accd[4];
        #pragma unroll
        for (int t = 0; t < 4; t++) { accp[t] = f4{0.f,0.f,0.f,0.f}; accd[t] = f4{0.f,0.f,0.f,0.f}; }
        #pragma unroll
        for (int ks = 0; ks < 4; ks++) {
            s8 a = a_from_f32(arow + ks * 32 + quad * 8);
            #pragma unroll
            for (int t = 0; t < 4; t++) {
                s8 b = *(const s8*)&WpT[(t * 16 + l16) * 136 + ks * 32 + quad * 8];
                accp[t] = __builtin_amdgcn_mfma_f32_16x16x32_bf16(a, b, accp[t], 0, 0, 0);
                if (ks < 2) {
                    s8 bd_ = *(const s8*)&WdT[(t * 16 + l16) * 72 + ks * 32 + quad * 8];
                    accd[t] = __builtin_amdgcn_mfma_f32_16x16x32_bf16(a, bd_, accd[t], 0, 0, 0);
                }
            }
        }
        int ty[4];
        #pragma unroll
        for (int r = 0; r < 4; r++) ty[r] = types[row0 + quad * 4 + r];
        float vv[4][4];
        #pragma unroll
        for (int t = 0; t < 4; t++) {
            int col = t * 16 + l16;
            float bpv = bp[col], bdv = bd[col];
            #pragma unroll
            for (int r = 0; r < 4; r++) {
                float v = ty[r] ? (accd[t][r] + bdv) : (accp[t][r] + bpv);
                vv[t][r] = v;
                h0f[(size_t)(row0 + quad * 4 + r) * 64 + col] = v;
                y0s[wv][(quad * 4 + r) * 72 + col] = (unsigned short)bf16r(v);
            }
        }
        s8 a0 = *(const s8*)&y0s[wv][l16 * 72 + quad * 8];
        s8 a1 = *(const s8*)&y0s[wv][l16 * 72 + 32 + quad * 8];
        f4 hw[4];
        #pragma unroll
        for (int t = 0; t < 4; t++) {
            hw[t] = f4{0.f,0.f,0.f,0.f};
            s8 b0 = *(const s8*)&WgT[(t * 16 + l16) * 72 + quad * 8];
            hw[t] = __builtin_amdgcn_mfma_f32_16x16x32_bf16(a0, b0, hw[t], 0, 0, 0);
            s8 b1_ = *(const s8*)&WgT[(t * 16 + l16) * 72 + 32 + quad * 8];
            hw[t] = __builtin_amdgcn_mfma_f32_16x16x32_bf16(a1, b1_, hw[t], 0, 0, 0);
        }
        #pragma unroll
        for (int t = 0; t < 4; t++) {
            int col = t * 16 + l16;
            float alv = al[col], arv = ar[col];
            #pragma unroll
            for (int r = 0; r < 4; r++) {
                int row = row0 + quad * 4 + r;
                float h = hw[t][r];
                P[(size_t)row * 64 + col] = bf16r(h) | (bf16r(vv[t][r]) << 16);
                float pl = h * alv, pr = h * arv;
                #pragma unroll
                for (int m = 1; m < 16; m <<= 1) {
                    pl += __shfl_xor(pl, m, 64);
                    pr += __shfl_xor(pr, m, 64);
                }
                if (l16 == 0) {
                    el[(size_t)row * 4 + t] = pl;
                    er[(size_t)row * 4 + t] = pr;
                }
            }
        }
    }
}

// ======= binB: per-bucket CSR fill (local degree hist + scan + gather), standalone ======
__global__ __launch_bounds__(256) void k_binB(
        int* __restrict__ row_start, const int* __restrict__ seg_off,
        const int* __restrict__ seg_cnt, const unsigned* __restrict__ gseg,
        int* __restrict__ csr_src, const int* __restrict__ bucket_tot) {
    __shared__ int spre[256];
    __shared__ int soff[NSEG];
    __shared__ int ss[256];
    __shared__ int kur[128];
    __shared__ int sred[4];
    int b = blockIdx.x;
    int t = threadIdx.x;
    // bucket start = sum of totals of buckets < b
    int bt = 0;
    for (int i = t; i < b; i += 256) bt += bucket_tot[i];
    #pragma unroll
    for (int o2 = 1; o2 < 64; o2 <<= 1) bt += __shfl_xor(bt, o2, 64);
    if ((t & 63) == 0) sred[t >> 6] = bt;
    // one segment per thread (NSEG=196 <= 256)
    int c0 = (t < NSEG) ? seg_cnt[t * NBKT + b] : 0;
    if (t < NSEG) soff[t] = seg_off[t * NBKT + b];
    ss[t] = c0;
    __syncthreads();
    int bstart = sred[0] + sred[1] + sred[2] + sred[3];
    for (int off = 1; off < 256; off <<= 1) {
        int u = (t >= off) ? ss[t - off] : 0;
        __syncthreads();
        ss[t] += u;
        __syncthreads();
    }
    spre[t] = ss[t] - c0;     // exclusive; t>=NSEG -> total (monotone pad)
    int cntb = ss[255];
    if (t < 128) kur[t] = 0;
    __syncthreads();
    // pass A: per-node degree histogram (LDS atomics over 128 counters)
    for (int idx = t; idx < cntb; idx += 256) {
        int lo = 0, hi = 255;
        #pragma unroll
        for (int s = 0; s < 8; s++) {
            int mid = (lo + hi + 1) >> 1;
            if (spre[mid] <= idx) lo = mid; else hi = mid - 1;
        }
        unsigned v = gseg[(size_t)lo * EPB + soff[lo] + (idx - spre[lo])];
        atomicAdd(&kur[v & 127], 1);
    }
    __syncthreads();
    // exclusive scan of 128 degrees -> cursors; write row_start
    int deg = (t < 128) ? kur[t] : 0;
    ss[t] = deg;
    __syncthreads();
    for (int off = 1; off < 256; off <<= 1) {
        int u = (t >= off) ? ss[t - off] : 0;
        __syncthreads();
        ss[t] += u;
        __syncthreads();
    }
    if (t < 128) {
        int cur = bstart + ss[t] - deg;
        kur[t] = cur;
        int d = (b << 7) + t;
        if (d < NN) row_start[d] = cur;
    }
    if (b == 0 && t == 0) row_start[NN] = EE;
    __syncthreads();
    // pass B: scatter (gseg slice is L2-warm from pass A)
    for (int idx = t; idx < cntb; idx += 256) {
        int lo = 0, hi = 255;
        #pragma unroll
        for (int s = 0; s < 8; s++) {
            int mid = (lo + hi + 1) >> 1;
            if (spre[mid] <= idx) lo = mid; else hi = mid - 1;
        }
        unsigned v = gseg[(size_t)lo * EPB + soff[lo] + (idx - spre[lo])];
        int p = atomicAdd(&kur[v & 127], 1);
        csr_src[p] = (int)(v >> 7);
    }
}

// ================= edge walk: 1 node/wave, exp once/edge, packed bf16 gather ======
template <int RELU>
__global__ void k_edges(const int* __restrict__ rows, const int* __restrict__ csr,
                        const unsigned* __restrict__ Pin,
                        const float* __restrict__ el, const float* __restrict__ er,
                        const float* __restrict__ gat_in, const float* __restrict__ gin_in,
                        const float* __restrict__ eps_p,
                        float* __restrict__ vgf, unsigned short* __restrict__ vgb,
                        unsigned short* __restrict__ xb) {
    __shared__ float ews[4][256];
    int wv = threadIdx.x >> 6, lane = threadIdx.x & 63;
    int n = blockIdx.x * 4 + wv;
    int st = rows[n], dg = rows[n + 1] - st;
    int hd = lane >> 4;
    float4 erv = *reinterpret_cast<const float4*>(er + (size_t)n * 4);
    float accg = 0.f, acci = 0.f, ssum = 0.f;
    for (int base = 0; base < dg; base += 64) {
        int rem = dg - base; if (rem > 64) rem = 64;
        int myi = 0;
        if (lane < rem) {
            myi = csr[st + base + lane];
            float4 lv = *reinterpret_cast<const float4*>(el + (size_t)myi * 4);
            float4 ev;
            ev.x = __expf(leaky(lv.x + erv.x));
            ev.y = __expf(leaky(lv.y + erv.y));
            ev.z = __expf(leaky(lv.z + erv.z));
            ev.w = __expf(leaky(lv.w + erv.w));
            *reinterpret_cast<float4*>(&ews[wv][lane * 4]) = ev;
        }
        int j = 0;
        for (; j + 4 <= rem; j += 4) {
            int s0 = __shfl(myi, j, 64),     s1 = __shfl(myi, j + 1, 64);
            int s2 = __shfl(myi, j + 2, 64), s3 = __shfl(myi, j + 3, 64);
            unsigned p0 = Pin[(size_t)s0 * 64 + lane];
            unsigned p1 = Pin[(size_t)s1 * 64 + lane];
            unsigned p2 = Pin[(size_t)s2 * 64 + lane];
            unsigned p3 = Pin[(size_t)s3 * 64 + lane];
            float a0 = ews[wv][(j + 0) * 4 + hd];
            float a1 = ews[wv][(j + 1) * 4 + hd];
            float a2 = ews[wv][(j + 2) * 4 + hd];
            float a3 = ews[wv][(j + 3) * 4 + hd];
            accg += a0 * lo16(p0) + a1 * lo16(p1) + a2 * lo16(p2) + a3 * lo16(p3);
            acci += hi16(p0) + hi16(p1) + hi16(p2) + hi16(p3);
            ssum += a0 + a1 + a2 + a3;
        }
        for (; j < rem; j++) {
            int s0 = __shfl(myi, j, 64);
            unsigned p0 = Pin[(size_t)s0 * 64 + lane];
            float a0 = ews[wv][j * 4 + hd];
            accg += a0 * lo16(p0); acci += hi16(p0); ssum += a0;
        }
    }
    float vg = accg / (ssum + 1e-9f) + gat_in[(size_t)n * 64 + lane];
    if (RELU) vg = fmaxf(vg, 0.f);
    float invd = 1.0f / fmaxf((float)dg, 1.0f);
    float x = (1.0f + eps_p[0]) * gin_in[(size_t)n * 64 + lane] + acci * invd;
    size_t off = (size_t)n * 64 + lane;
    vgf[off] = vg;
    vgb[off] = (unsigned short)bf16r(vg);
    xb[off] = (unsigned short)bf16r(x);
}

// ====== k_mlp: GIN MLP (y1 in LDS) + (L==0: GAT-l1 pre | L==1: fused MoE routing) ======
template <int L>
__global__ __launch_bounds__(256) void k_mlp(const unsigned short* __restrict__ Gx,
        const unsigned short* __restrict__ Eb,
        const float* __restrict__ W1, const float* __restrict__ b1,
        const float* __restrict__ W2, const float* __restrict__ b2,
        const float* __restrict__ gatW, const float* __restrict__ al,
        const float* __restrict__ ar,
        unsigned short* __restrict__ Fb, float* __restrict__ Cf,
        unsigned* __restrict__ P, float* __restrict__ el, float* __restrict__ er,
        const float* __restrict__ Zg, const float* __restrict__ ggW,
        const float* __restrict__ ggb, const float* __restrict__ igW,
        const float* __restrict__ igb,
        float* __restrict__ wgtg, float* __restrict__ wgti,
        float* __restrict__ stats) {
    __shared__ unsigned short W1T[64 * 72];
    __shared__ unsigned short W2T[64 * 72];
    __shared__ unsigned short WgT[(L == 0) ? 64 * 72 : 64];
    __shared__ unsigned short y1s[4][16 * 72];
    __shared__ float sstat[16];
    if (L == 1 && threadIdx.x < 16) sstat[threadIdx.x] = 0.f;
    for (int idx = threadIdx.x; idx < 64 * 64; idx += 256) {
        int k = idx >> 6, n = idx & 63;
        W1T[n * 72 + k] = (unsigned short)bf16r(W1[idx]);
        W2T[n * 72 + k] = (unsigned short)bf16r(W2[idx]);
        if (L == 0) WgT[n * 72 + k] = (unsigned short)bf16r(gatW[idx]);
    }
    __syncthreads();
    int wv = threadIdx.x >> 6, lane = threadIdx.x & 63;
    int quad = lane >> 4, l16 = lane & 15;
    int gw = blockIdx.x * 4 + wv;
    int mtEnd = gw * 2 + 2; if (mtEnd > 3125) mtEnd = 3125;
    float sp[2][4] = {{0,0,0,0},{0,0,0,0}};
    float sh[2][4] = {{0,0,0,0},{0,0,0,0}};
    for (int mt = gw * 2; mt < mtEnd; mt++) {
        int row0 = mt * 16;
        const unsigned short* arow = Gx + (size_t)(row0 + l16) * 64;
        s8 a0 = *(const s8*)(arow + quad * 8);
        s8 a1 = *(const s8*)(arow + 32 + quad * 8);
        f4 acc1[4];
        #pragma unroll
        for (int t = 0; t < 4; t++) {
            acc1[t] = f4{0.f,0.f,0.f,0.f};
            s8 b0 = *(const s8*)&W1T[(t * 16 + l16) * 72 + quad * 8];
            acc1[t] = __builtin_amdgcn_mfma_f32_16x16x32_bf16(a0, b0, acc1[t], 0, 0, 0);
            s8 b1_ = *(const s8*)&W1T[(t * 16 + l16) * 72 + 32 + quad * 8];
            acc1[t] = __builtin_amdgcn_mfma_f32_16x16x32_bf16(a1, b1_, acc1[t], 0, 0, 0);
        }
        #pragma unroll
        for (int t = 0; t < 4; t++) {
            float b1v = b1[t * 16 + l16];
            #pragma unroll
            for (int r = 0; r < 4; r++) {
                float v = fmaxf(acc1[t][r] + b1v, 0.f);
                y1s[wv][(quad * 4 + r) * 72 + t * 16 + l16] = (unsigned short)bf16r(v);
            }
        }
        s8 c0 = *(const s8*)&y1s[wv][l16 * 72 + quad * 8];
        s8 c1 = *(const s8*)&y1s[wv][l16 * 72 + 32 + quad * 8];
        f4 acc2[4];
        #pragma unroll
        for (int t = 0; t < 4; t++) {
            acc2[t] = f4{0.f,0.f,0.f,0.f};
            s8 b0 = *(const s8*)&W2T[(t * 16 + l16) * 72 + quad * 8];
            acc2[t] = __builtin_amdgcn_mfma_f32_16x16x32_bf16(c0, b0, acc2[t], 0, 0, 0);
            s8 b1_ = *(const s8*)&W2T[(t * 16 + l16) * 72 + 32 + quad * 8];
            acc2[t] = __builtin_amdgcn_mfma_f32_16x16x32_bf16(c1, b1_, acc2[t], 0, 0, 0);
        }
        unsigned short vb[4][4];
        float vout[4][4];
        #pragma unroll
        for (int t = 0; t < 4; t++) {
            int col = t * 16 + l16;
            float b2v = b2[col];
            #pragma unroll
            for (int r = 0; r < 4; r++) {
                float v = acc2[t][r] + b2v;
                if (L == 0) v = fmaxf(v, 0.f);
                size_t off = (size_t)(row0 + quad * 4 + r) * 64 + col;
                unsigned short vb16 = (unsigned short)bf16r(v);
                vb[t][r] = vb16;
                vout[t][r] = v;
                Fb[off] = vb16;
                if (L == 0) Cf[off] = v;
            }
        }
        if (L == 0) {
            const unsigned short* erow = Eb + (size_t)(row0 + l16) * 64;
            s8 e0 = *(const s8*)(erow + quad * 8);
            s8 e1 = *(const s8*)(erow + 32 + quad * 8);
            f4 hw[4];
            #pragma unroll
            for (int t = 0; t < 4; t++) {
                hw[t] = f4{0.f,0.f,0.f,0.f};
                s8 b0 = *(const s8*)&WgT[(t * 16 + l16) * 72 + quad * 8];
                hw[t] = __builtin_amdgcn_mfma_f32_16x16x32_bf16(e0, b0, hw[t], 0, 0, 0);
                s8 b1_ = *(const s8*)&WgT[(t * 16 + l16) * 72 + 32 + quad * 8];
                hw[t] = __builtin_amdgcn_mfma_f32_16x16x32_bf16(e1, b1_, hw[t], 0, 0, 0);
            }
            #pragma unroll
            for (int t = 0; t < 4; t++) {
                int col = t * 16 + l16;
                float alv = al[col], arv = ar[col];
                #pragma unroll
                for (int r = 0; r < 4; r++) {
                    int row = row0 + quad * 4 + r;
                    float h = hw[t][r];
                    P[(size_t)row * 64 + col] = bf16r(h) | ((unsigned)vb[t][r] << 16);
                    float pl = h * alv, pr = h * arv;
                    #pragma unroll
                    for (int m = 1; m < 16; m <<= 1) {
                        pl += __shfl_xor(pl, m, 64);
                        pr += __shfl_xor(pr, m, 64);
                    }
                    if (l16 == 0) {
                        el[(size_t)row * 4 + t] = pl;
                        er[(size_t)row * 4 + t] = pr;
                    }
                }
            }
        } else {
            // fused MoE routing: zg from global (B), zi from registers
            #pragma unroll
            for (int r = 0; r < 4; r++) {
                int row = row0 + quad * 4 + r;
                float pg[4] = {0,0,0,0}, pi[4] = {0,0,0,0};
                #pragma unroll
                for (int t = 0; t < 4; t++) {
                    int col = t * 16 + l16;
                    float zgv = Zg[(size_t)row * 64 + col];
                    float ziv = vout[t][r];
                    #pragma unroll
                    for (int e = 0; e < 4; e++) {
                        pg[e] += zgv * ggW[col * 4 + e];
                        pi[e] += ziv * igW[col * 4 + e];
                    }
                }
                #pragma unroll
                for (int m = 1; m < 16; m <<= 1) {
                    #pragma unroll
                    for (int e = 0; e < 4; e++) {
                        pg[e] += __shfl_xor(pg[e], m, 64);
                        pi[e] += __shfl_xor(pi[e], m, 64);
                    }
                }
                if (l16 == 0) {
                    #pragma unroll
                    for (int q = 0; q < 2; q++) {
                        float lg0 = (q ? pi[0] + igb[0] : pg[0] + ggb[0]);
                        float lg1 = (q ? pi[1] + igb[1] : pg[1] + ggb[1]);
                        float lg2 = (q ? pi[2] + igb[2] : pg[2] + ggb[2]);
                        float lg3 = (q ? pi[3] + igb[3] : pg[3] + ggb[3]);
                        float mx = fmaxf(fmaxf(lg0, lg1), fmaxf(lg2, lg3));
                        float ex0 = __expf(lg0 - mx), ex1 = __expf(lg1 - mx);
                        float ex2 = __expf(lg2 - mx), ex3 = __expf(lg3 - mx);
                        float inv = 1.0f / (ex0 + ex1 + ex2 + ex3);
                        float pr4[4] = {ex0 * inv, ex1 * inv, ex2 * inv, ex3 * inv};
                        int i1 = 0; float v1 = pr4[0];
                        #pragma unroll
                        for (int t = 1; t < 4; t++) if (pr4[t] > v1) { v1 = pr4[t]; i1 = t; }
                        int i2 = -1; float v2 = -1.f;
                        #pragma unroll
                        for (int t = 0; t < 4; t++) if (t != i1 && pr4[t] > v2) { v2 = pr4[t]; i2 = t; }
                        float wsum = v1 + v2;
                        float wq[4] = {0.f, 0.f, 0.f, 0.f};
                        wq[i1] = v1 / wsum; wq[i2] = v2 / wsum;
                        float* WD = q ? wgti : wgtg;
                        *reinterpret_cast<float4*>(WD + (size_t)row * 4) =
                            float4{wq[0], wq[1], wq[2], wq[3]};
                        #pragma unroll
                        for (int t = 0; t < 4; t++) sp[q][t] += pr4[t];
                        sh[q][i1] += 1.f; sh[q][i2] += 1.f;
                    }
                }
            }
        }
    }
    if (L == 1) {
        __syncthreads();
        if (l16 == 0) {
            #pragma unroll
            for (int q = 0; q < 2; q++)
                #pragma unroll
                for (int e = 0; e < 4; e++) {
                    atomicAdd(&sstat[q * 8 + e], sp[q][e]);
                    atomicAdd(&sstat[q * 8 + 4 + e], sh[q][e]);
                }
        }
        __syncthreads();
        if (threadIdx.x < 16) atomicAdd(&stats[threadIdx.x], sstat[threadIdx.x]);
    }
}

// ======= k_tail: dense-all experts (both problems) + fusion gate + aux, one kernel ======
// MoE outputs stay in registers; ub bf16 via same-wave L2 round-trip for layout transpose.
__global__ __launch_bounds__(256) void k_tail(const unsigned short* __restrict__ Eb,
        const unsigned short* __restrict__ Fb,
        const float* __restrict__ g_eW1, const float* __restrict__ g_eb1,
        const float* __restrict__ g_eW2, const float* __restrict__ g_eb2,
        const float* __restrict__ i_eW1, const float* __restrict__ i_eb1,
        const float* __restrict__ i_eW2, const float* __restrict__ i_eb2,
        const float* __restrict__ wgtg, const float* __restrict__ wgti,
        const float* __restrict__ W1, const float* __restrict__ b1,
        const float* __restrict__ W2, const float* __restrict__ b2,
        unsigned short* __restrict__ ub, float* __restrict__ out,
        const float* __restrict__ stats) {
    __shared__ unsigned short wbuf[4 * 32 * 72 + 4 * 64 * 40];  // 38912 B; w1t | w2t; fusion wts alias
    __shared__ unsigned short y1s[4][16 * 72];                  // 9216 B
    int wv = threadIdx.x >> 6, lane = threadIdx.x & 63;
    int quad = lane >> 4, l16 = lane & 15;
    int gw = blockIdx.x * 4 + wv;
    int mt0 = gw * 2;
    f4 moe[2][2][4];   // [problem][mtile][t] - fully unrolled indices (no scratch)
    #pragma unroll
    for (int p = 0; p < 2; p++)
        #pragma unroll
        for (int m = 0; m < 2; m++)
            #pragma unroll
            for (int t = 0; t < 4; t++) moe[p][m][t] = f4{0.f,0.f,0.f,0.f};
    #pragma unroll
    for (int p = 0; p < 2; p++) {
        const unsigned short* Ab = p ? Fb : Eb;
        const float* eW1 = p ? i_eW1 : g_eW1;
        const float* eb1 = p ? i_eb1 : g_eb1;
        const float* eW2 = p ? i_eW2 : g_eW2;
        const float* eb2 = p ? i_eb2 : g_eb2;
        const float* wgt = p ? wgti : wgtg;
        int qoff = p ? 64 : 0;
        if (p) __syncthreads();     // drain previous problem's wbuf reads
        for (int g = threadIdx.x; g < 8192; g += 256) {
            int e = g >> 11, rem = g & 2047;
            int k = rem >> 5, n = rem & 31;
            wbuf[e * 2304 + n * 72 + k] = (unsigned short)bf16r(eW1[g]);
        }
        for (int g = threadIdx.x; g < 8192; g += 256) {
            int e = g >> 11, rem = g & 2047;
            int k = rem >> 6, n = rem & 63;
            wbuf[9216 + e * 2560 + n * 40 + k] = (unsigned short)bf16r(eW2[g]);
        }
        __syncthreads();
        #pragma unroll
        for (int m = 0; m < 2; m++) {
            int mt = mt0 + m;
            if (mt < 3125) {
                int row0 = mt * 16;
                const unsigned short* arow = Ab + (size_t)(row0 + l16) * 64;
                s8 a0 = *(const s8*)(arow + quad * 8);
                s8 a1 = *(const s8*)(arow + 32 + quad * 8);
                for (int e = 0; e < 4; e++) {
                    f4 acc1[2];
                    #pragma unroll
                    for (int t = 0; t < 2; t++) {
                        acc1[t] = f4{0.f,0.f,0.f,0.f};
                        s8 b0 = *(const s8*)&wbuf[e * 2304 + (t * 16 + l16) * 72 + quad * 8];
                        acc1[t] = __builtin_amdgcn_mfma_f32_16x16x32_bf16(a0, b0, acc1[t], 0, 0, 0);
                        s8 b1_ = *(const s8*)&wbuf[e * 2304 + (t * 16 + l16) * 72 + 32 + quad * 8];
                        acc1[t] = __builtin_amdgcn_mfma_f32_16x16x32_bf16(a1, b1_, acc1[t], 0, 0, 0);
                    }
                    #pragma unroll
                    for (int t = 0; t < 2; t++) {
                        float b1v = eb1[e * 32 + t * 16 + l16];
                        #pragma unroll
                        for (int r = 0; r < 4; r++) {
                            float v = fmaxf(acc1[t][r] + b1v, 0.f);
                            y1s[wv][(quad * 4 + r) * 40 + t * 16 + l16] = (unsigned short)bf16r(v);
                        }
                    }
                    s8 a2 = *(const s8*)&y1s[wv][l16 * 40 + quad * 8];
                    f4 acc2[4];
                    #pragma unroll
                    for (int t = 0; t < 4; t++) {
                        acc2[t] = f4{0.f,0.f,0.f,0.f};
                        s8 b2_ = *(const s8*)&wbuf[9216 + e * 2560 + (t * 16 + l16) * 40 + quad * 8];
                        acc2[t] = __builtin_amdgcn_mfma_f32_16x16x32_bf16(a2, b2_, acc2[t], 0, 0, 0);
                    }
                    #pragma unroll
                    for (int t = 0; t < 4; t++) {
                        float b2v = eb2[e * 64 + t * 16 + l16];
                        #pragma unroll
                        for (int r = 0; r < 4; r++) {
                            float we = wgt[(size_t)(row0 + quad * 4 + r) * 4 + e];
                            moe[p][m][t][r] += we * (acc2[t][r] + b2v);
                        }
                    }
                }
                #pragma unroll
                for (int t = 0; t < 4; t++) {
                    int col = t * 16 + l16;
                    #pragma unroll
                    for (int r = 0; r < 4; r++) {
                        int row = row0 + quad * 4 + r;
                        ub[(size_t)row * 128 + qoff + col] = (unsigned short)bf16r(moe[p][m][t][r]);
                    }
                }
            }
        }
    }
    __syncthreads();
    // ---- fusion gate: stage weights into wbuf (aliased) ----
    for (int idx = threadIdx.x; idx < 128 * 64; idx += 256) {
        int k = idx >> 6, n = idx & 63;
        wbuf[n * 136 + k] = (unsigned short)bf16r(W1[idx]);
    }
    for (int idx = threadIdx.x; idx < 64 * 64; idx += 256) {
        int k = idx >> 6, n = idx & 63;
        wbuf[8704 + n * 72 + k] = (unsigned short)bf16r(W2[idx]);
    }
    __syncthreads();
    #pragma unroll
    for (int m = 0; m < 2; m++) {
        int mt = mt0 + m;
        if (mt < 3125) {
            int row0 = mt * 16;
            const unsigned short* arow = ub + (size_t)(row0 + l16) * 128;
            f4 acc1[4];
            #pragma unroll
            for (int t = 0; t < 4; t++) acc1[t] = f4{0.f,0.f,0.f,0.f};
            #pragma unroll
            for (int ks = 0; ks < 4; ks++) {
                s8 a = *(const s8*)(arow + ks * 32 + quad * 8);
                #pragma unroll
                for (int t = 0; t < 4; t++) {
                    s8 b = *(const s8*)&wbuf[(t * 16 + l16) * 136 + ks * 32 + quad * 8];
                    acc1[t] = __builtin_amdgcn_mfma_f32_16x16x32_bf16(a, b, acc1[t], 0, 0, 0);
                }
            }
            #pragma unroll
            for (int t = 0; t < 4; t++) {
                float b1v = b1[t * 16 + l16];
                #pragma unroll
                for (int r = 0; r < 4; r++) {
                    float v = fmaxf(acc1[t][r] + b1v, 0.f);
                    y1s[wv][(quad * 4 + r) * 72 + t * 16 + l16] = (unsigned short)bf16r(v);
                }
            }
            f4 acc2[4];
            #pragma unroll
            for (int t = 0; t < 4; t++) acc2[t] = f4{0.f,0.f,0.f,0.f};
            #pragma unroll
            for (int ks = 0; ks < 2; ks++) {
                s8 a = *(const s8*)&y1s[wv][l16 * 72 + ks * 32 + quad * 8];
                #pragma unroll
                for (int t = 0; t < 4; t++) {
                    s8 b = *(const s8*)&wbuf[8704 + (t * 16 + l16) * 72 + ks * 32 + quad * 8];
                    acc2[t] = __builtin_amdgcn_mfma_f32_16x16x32_bf16(a, b, acc2[t], 0, 0, 0);
                }
            }
            #pragma unroll
            for (int t = 0; t < 4; t++) {
                int col = t * 16 + l16;
                float b2v = b2[col];
                #pragma unroll
                for (int r = 0; r < 4; r++) {
                    int row = row0 + quad * 4 + r;
                    float g = 1.0f / (1.0f + __expf(-(acc2[t][r] + b2v)));
                    float zgv = moe[0][m][t][r];
                    float ziv = moe[1][m][t][r];
                    out[(size_t)row * 64 + col] = g * zgv * ziv + (1.0f - g) * g;
                }
            }
        }
    }
    if (blockIdx.x == 0 && threadIdx.x < 64) {
        int t = threadIdx.x;
        float s = (t < 16) ? stats[t] : 0.f;
        float aux = 0.f;
        for (int q = 0; q < 2; q++) {
            float a = 0.f;
            for (int e = 0; e < 4; e++) {
                float pr = __shfl(s, q * 8 + e, 64);
                float f  = __shfl(s, q * 8 + 4 + e, 64);
                a += (f / (float)NN) * (pr / (float)NN);
            }
            aux += 4.0f * a;
        }
        if (t == 0) out[(size_t)NN * 64] = aux;
    }
}

extern "C" void kernel_launch(void* const* d_in, const int* in_sizes, int n_in,
                              void* d_out, int out_size, void* d_ws, size_t ws_size,
                              hipStream_t stream) {
    (void)in_sizes; (void)n_in; (void)out_size; (void)ws_size;
    const float* features  = (const float*)d_in[0];
    const int*   node_types= (const int*)d_in[1];
    const int*   src       = (const int*)d_in[2];
    const int*   dst       = (const int*)d_in[3];
    const float* W_person  = (const float*)d_in[4];
    const float* b_person  = (const float*)d_in[5];
    const float* W_disease = (const float*)d_in[6];
    const float* b_disease = (const float*)d_in[7];
    const float* gat_W     = (const float*)d_in[8];
    const float* gat_al    = (const float*)d_in[9];
    const float* gat_ar    = (const float*)d_in[10];
    const float* gin_eps   = (const float*)d_in[11];
    const float* gin_W1    = (const float*)d_in[12];
    const float* gin_b1    = (const float*)d_in[13];
    const float* gin_W2    = (const float*)d_in[14];
    const float* gin_b2    = (const float*)d_in[15];
    const float* gat_gW    = (const float*)d_in[16];
    const float* gat_gb    = (const float*)d_in[17];
    const float* gat_eW1   = (const float*)d_in[18];
    const float* gat_eb1   = (const float*)d_in[19];
    const float* gat_eW2   = (const float*)d_in[20];
    const float* gat_eb2   = (const float*)d_in[21];
    const float* gin_gW    = (const float*)d_in[22];
    const float* gin_gb    = (const float*)d_in[23];
    const float* gin_eW1   = (const float*)d_in[24];
    const float* gin_eb1   = (const float*)d_in[25];
    const float* gin_eW2   = (const float*)d_in[26];
    const float* gin_eb2   = (const float*)d_in[27];
    const float* fg_W1     = (const float*)d_in[28];
    const float* fg_b1     = (const float*)d_in[29];
    const float* fg_W2     = (const float*)d_in[30];
    const float* fg_b2     = (const float*)d_in[31];
    float* out = (float*)d_out;

    float* ws = (float*)d_ws;
    size_t o = 0;
    float* A = ws + o; o += (size_t)NN * 64;        // h0f; later ub (bf16 NN x 128)
    float* B = ws + o; o += (size_t)NN * 64;        // vg f32 chain (zg for routing)
    float* C = ws + o; o += (size_t)NN * 64;        // gin l0 f32
    unsigned short* E  = (unsigned short*)(ws + o); o += (size_t)NN * 32;  // vgb
    unsigned short* F  = (unsigned short*)(ws + o); o += (size_t)NN * 32;  // ginb
    unsigned short* G  = (unsigned short*)(ws + o); o += (size_t)NN * 32;  // xb
    unsigned* P = (unsigned*)(ws + o); o += (size_t)NN * 64;  // packed hW|gin
    float* el = ws + o; o += (size_t)NN * 4;
    float* er = ws + o; o += (size_t)NN * 4;
    float* wgtg = ws + o; o += (size_t)NN * 4;
    float* wgti = ws + o; o += (size_t)NN * 4;
    // zeroed region: bucket_tot | stats (single tiny memset)
    int* bucket_tot = (int*)(ws + o); o += 392;
    float* stats    = ws + o; o += 16;
    int* row_start = (int*)(ws + o); o += NN + 4;
    int* csr_src   = (int*)(ws + o); o += EE;
    int* seg_off   = (int*)(ws + o); o += NSEG * NBKT + 64;
    int* seg_cnt   = (int*)(ws + o); o += NSEG * NBKT + 64;
    unsigned* gseg = (unsigned*)(ws + o); o += (size_t)NSEG * EPB;

    unsigned short* ub = (unsigned short*)A;  // reuse after edges(l0)

    const int NB_node = NN / 4;     // 12500

    hipMemsetAsync(bucket_tot, 0, sizeof(int) * 392 + sizeof(float) * 16, stream);

    // fused: binA counting sort (blocks 0..195) || projection/GAT-l0 pre (blocks 196..586)
    k_binA_pre<<<NSEG + NBG, 256, 0, stream>>>(src, dst, seg_off, seg_cnt, gseg, bucket_tot,
                                               features, node_types, W_person, b_person,
                                               W_disease, b_disease, gat_W, gat_al, gat_ar,
                                               A, P, el, er);

    // binB: per-bucket CSR fill (391 blocks, small LDS)
    k_binB<<<NBKT, 256, 0, stream>>>(row_start, seg_off, seg_cnt, gseg, csr_src, bucket_tot);

    // ---- layer 0 ----
    k_edges<1><<<NB_node, 256, 0, stream>>>(row_start, csr_src, P, el, er, A, A,
                                            gin_eps, B, E, G);
    k_mlp<0><<<NBG, 256, 0, stream>>>(G, E, gin_W1, gin_b1, gin_W2, gin_b2,
                                      gat_W + 4096, gat_al + 64, gat_ar + 64,
                                      F, C, P, el, er,
                                      nullptr, nullptr, nullptr, nullptr, nullptr,
                                      nullptr, nullptr, nullptr);

    // ---- layer 1 (+fused MoE routing) ----
    k_edges<0><<<NB_node, 256, 0, stream>>>(row_start, csr_src, P, el, er, B, C,
                                            gin_eps + 1, B, E, G);
    k_mlp<1><<<NBG, 256, 0, stream>>>(G, nullptr, gin_W1 + 4096, gin_b1 + 64,
                                      gin_W2 + 4096, gin_b2 + 64,
                                      nullptr, nullptr, nullptr,
                                      F, nullptr, nullptr, nullptr, nullptr,
                                      B, gat_gW, gat_gb, gin_gW, gin_gb,
                                      wgtg, wgti, stats);

    // ---- tail: experts (both problems) + fusion + aux in one kernel ----
    k_tail<<<NBT, 256, 0, stream>>>(E, F,
                                    gat_eW1, gat_eb1, gat_eW2, gat_eb2,
                                    gin_eW1, gin_eb1, gin_eW2, gin_eb2,
                                    wgtg, wgti, fg_W1, fg_b1, fg_W2, fg_b2,
                                    ub, out, stats);
}